// Round 3
// baseline (347.547 us; speedup 1.0000x reference)
//
#include <hip/hip_runtime.h>

#define DIM 64
#define GPW 4    // 16-row groups per wave in gemm
#define BSHIFT 9
#define BSPAN 512      // nodes per bucket
#define MAXNB 512      // max buckets (N <= 262144; here N=200000 -> NB=391)

typedef __attribute__((ext_vector_type(8))) __bf16 bf16x8;
typedef __attribute__((ext_vector_type(4))) __bf16 bf16x4;
typedef __attribute__((ext_vector_type(4))) float f32x4;

__device__ __forceinline__ f32x4 mfma16(bf16x8 a, bf16x8 b, f32x4 c) {
    return __builtin_amdgcn_mfma_f32_16x16x32_bf16(a, b, c, 0, 0, 0);
}

__device__ __forceinline__ float bf2f(unsigned short u) {
    return __uint_as_float((unsigned)u << 16);
}

// ---------- hierarchical CSR build (bucket -> node counting sort) ----------

__global__ void zerob_kernel(int* __restrict__ b) { b[threadIdx.x] = 0; }

__global__ __launch_bounds__(512) void bucket_count_kernel(
    const int* __restrict__ ei, int* __restrict__ bcnt, int E_, int NB) {
    __shared__ int hist[MAXNB];
    int tid = threadIdx.x;
    for (int i = tid; i < NB; i += 512) hist[i] = 0;
    __syncthreads();
    int chunk = (E_ + gridDim.x - 1) / gridDim.x;
    int e0 = blockIdx.x * chunk, e1 = min(E_, e0 + chunk);
    for (int e = e0 + tid; e < e1; e += 512)
        atomicAdd(&hist[ei[E_ + e] >> BSHIFT], 1);
    __syncthreads();
    for (int i = tid; i < NB; i += 512)
        if (hist[i]) atomicAdd(&bcnt[i], hist[i]);
}

__global__ __launch_bounds__(512) void bucket_scan_kernel(
    const int* __restrict__ bcnt, int* __restrict__ bptr, int* __restrict__ bcur,
    int* __restrict__ rowptr, int NB, int N_, int E_) {
    __shared__ int sm[512];
    int tid = threadIdx.x;
    int v = (tid < NB) ? bcnt[tid] : 0;
    sm[tid] = v;
    __syncthreads();
    for (int off = 1; off < 512; off <<= 1) {
        int t = 0;
        if (tid >= off) t = sm[tid - off];
        __syncthreads();
        if (tid >= off) sm[tid] += t;
        __syncthreads();
    }
    if (tid < NB) {
        int ex = sm[tid] - v;
        bptr[tid] = ex;
        bcur[tid] = ex;
    }
    if (tid == 0) { bptr[NB] = E_; rowptr[N_] = E_; }
}

__global__ __launch_bounds__(512) void scatter_kernel(
    const int* __restrict__ ei, int* __restrict__ bcur,
    unsigned* __restrict__ packed, int E_, int NB) {
    __shared__ int h[MAXNB];
    int tid = threadIdx.x;
    int chunk = (E_ + gridDim.x - 1) / gridDim.x;
    int e0 = blockIdx.x * chunk, e1 = min(E_, e0 + chunk);
    for (int i = tid; i < NB; i += 512) h[i] = 0;
    __syncthreads();
    for (int e = e0 + tid; e < e1; e += 512)
        atomicAdd(&h[ei[E_ + e] >> BSHIFT], 1);
    __syncthreads();
    for (int i = tid; i < NB; i += 512) {
        int c = h[i];
        h[i] = c ? atomicAdd(&bcur[i], c) : 0;
    }
    __syncthreads();
    for (int e = e0 + tid; e < e1; e += 512) {
        int s = ei[e], d = ei[E_ + e];
        int b = d >> BSHIFT;
        int pos = atomicAdd(&h[b], 1);
        packed[pos] = ((unsigned)s << BSHIFT) | (unsigned)(d & (BSPAN - 1));
    }
}

__global__ __launch_bounds__(256) void bucket_sort_kernel(
    const unsigned* __restrict__ packed, const int* __restrict__ bptr,
    int* __restrict__ rowptr, int* __restrict__ srcs,
    float* __restrict__ dinv, int N_) {
    __shared__ int cnt[BSPAN];
    __shared__ int sc[256];
    int tid = threadIdx.x;
    int b = blockIdx.x;
    int beg = bptr[b], end = bptr[b + 1];
    int node0 = b << BSHIFT;
    int nn = min(BSPAN, N_ - node0);
    cnt[tid] = 0; cnt[tid + 256] = 0;
    __syncthreads();
    for (int i = beg + tid; i < end; i += 256)
        atomicAdd(&cnt[packed[i] & (BSPAN - 1)], 1);
    __syncthreads();
    int degA = cnt[tid], degB = cnt[tid + 256];
    int a0 = cnt[2 * tid], a1 = cnt[2 * tid + 1];
    if (tid < nn) dinv[node0 + tid] = rsqrtf((float)(1 + degA));
    if (tid + 256 < nn) dinv[node0 + tid + 256] = rsqrtf((float)(1 + degB));
    int tot = a0 + a1;
    sc[tid] = tot;
    __syncthreads();
    for (int off = 1; off < 256; off <<= 1) {
        int t = 0;
        if (tid >= off) t = sc[tid - off];
        __syncthreads();
        if (tid >= off) sc[tid] += t;
        __syncthreads();
    }
    int ex = sc[tid] - tot;
    cnt[2 * tid] = ex;
    cnt[2 * tid + 1] = ex + a0;
    __syncthreads();
    if (tid < nn) rowptr[node0 + tid] = beg + cnt[tid];
    if (tid + 256 < nn) rowptr[node0 + tid + 256] = beg + cnt[tid + 256];
    __syncthreads();
    for (int i = beg + tid; i < end; i += 256) {
        unsigned p = packed[i];
        int pos = atomicAdd(&cnt[p & (BSPAN - 1)], 1);
        srcs[beg + pos] = (int)(p >> BSHIFT);
    }
}

// ---------- algebraic-restructure kernels ----------
// H2 = (A^2 X) (W1 W2) + (A 1)(b1^T W2) + 1 b2^T

// W' = W1*W2 (fp32), c = b1^T W2. One block.
__global__ __launch_bounds__(256) void prep_kernel(
    const float* __restrict__ W1, const float* __restrict__ W2,
    const float* __restrict__ b1, float* __restrict__ Wp,
    float* __restrict__ c) {
    int t = threadIdx.x;
#pragma unroll
    for (int e = 0; e < 16; ++e) {
        int idx = t * 16 + e;
        int k = idx >> 6, n = idx & 63;
        float s = 0.f;
        for (int m = 0; m < 64; ++m) s = fmaf(W1[k * 64 + m], W2[m * 64 + n], s);
        Wp[idx] = s;
    }
    if (t < 64) {
        float s = 0.f;
        for (int k = 0; k < 64; ++k) s = fmaf(b1[k], W2[k * 64 + t], s);
        c[t] = s;
    }
}

// g = bf16(dinv * x). Pure streaming cast (8 elems/thread).
__global__ __launch_bounds__(256) void cast_kernel(
    const float* __restrict__ ua, const float* __restrict__ ub, int split,
    const float* __restrict__ dinv, __bf16* __restrict__ g, int n) {
    int idx = blockIdx.x * 256 + threadIdx.x;
    int row = idx >> 3, off = (idx & 7) * 8;
    if (row >= n) return;
    const float* x = (row < split) ? ua + (size_t)row * DIM
                                   : ub + (size_t)(row - split) * DIM;
    float dn = dinv[row];
    f32x4 v0 = *(const f32x4*)(x + off);
    f32x4 v1 = *(const f32x4*)(x + off + 4);
    bf16x8 o;
#pragma unroll
    for (int j = 0; j < 4; ++j) {
        o[j]     = (__bf16)(v0[j] * dn);
        o[j + 4] = (__bf16)(v1[j] * dn);
    }
    *(bf16x8*)(g + (size_t)row * DIM + off) = o;
}

// Aggregation: rowsum over {self} U N(node) of bf16 rows of `in`.
// FIRST:  out = bf16(dinv^2 * rowsum);  r[node] = dinv * sum(dinv over set)
// !FIRST: out = bf16(dinv   * rowsum)
// Wave = 4 groups x 16 lanes; 16 edge slots/iter (4 x 512 B in flight);
// P(deg+1 > 16) ~ 3e-4, so ~all nodes finish gathers in one round.
template <bool FIRST>
__global__ __launch_bounds__(256) void agg_kernel(
    const int* __restrict__ rowptr, const int* __restrict__ srcs,
    const __bf16* __restrict__ in, const float* __restrict__ dinv,
    __bf16* __restrict__ outrow, float* __restrict__ r, int n) {
    int lane = threadIdx.x & 63;
    int grp = lane >> 4;
    int t4 = lane & 15;
    int node = blockIdx.x * 4 + __builtin_amdgcn_readfirstlane(threadIdx.x >> 6);
    if (node >= n) return;
    int beg = rowptr[node], end = rowptr[node + 1];
    float dn = dinv[node];

    float a0 = 0.f, a1 = 0.f, a2 = 0.f, a3 = 0.f, sd = 0.f;
    for (int base = beg - 1; base < end; base += 16) {
#pragma unroll
        for (int k = 0; k < 4; ++k) {
            int i = base + grp + 4 * k;
            int s = node;                       // i == beg-1 -> self row
            if (i >= beg && i < end) s = srcs[i];
            ushort4 v = make_ushort4(0, 0, 0, 0);
            float dv = 0.f;
            if (i < end) {
                v = *(const ushort4*)(in + (size_t)s * DIM + t4 * 4);
                if constexpr (FIRST)
                    if (t4 == 0) dv = dinv[s];
            }
            a0 += bf2f(v.x); a1 += bf2f(v.y);
            a2 += bf2f(v.z); a3 += bf2f(v.w);
            if constexpr (FIRST) sd += dv;
        }
    }
#pragma unroll
    for (int off = 16; off <= 32; off <<= 1) {
        a0 += __shfl_xor(a0, off);
        a1 += __shfl_xor(a1, off);
        a2 += __shfl_xor(a2, off);
        a3 += __shfl_xor(a3, off);
        if constexpr (FIRST) sd += __shfl_xor(sd, off);
    }
    float scale = FIRST ? dn * dn : dn;
    if (grp == 0) {
        bf16x4 o;
        o[0] = (__bf16)(a0 * scale); o[1] = (__bf16)(a1 * scale);
        o[2] = (__bf16)(a2 * scale); o[3] = (__bf16)(a3 * scale);
        *(bf16x4*)(outrow + (size_t)node * DIM + t4 * 4) = o;
        if constexpr (FIRST)
            if (t4 == 0) r[node] = dn * sd;
    }
}

// out(fp32) = z(bf16) @ W' + r*c + b2.   MFMA 16x16x32 bf16.
__global__ __launch_bounds__(256) void gemm_kernel(
    const __bf16* __restrict__ z, const float* __restrict__ Wp,
    const float* __restrict__ c, const float* __restrict__ b2,
    const float* __restrict__ r, float* __restrict__ out, int n, int ngroups) {
    int lane = threadIdx.x & 63;
    int q = lane >> 4, t = lane & 15;
    int wv = __builtin_amdgcn_readfirstlane(threadIdx.x >> 6);
    int g0 = (blockIdx.x * 4 + wv) * GPW;
    if (g0 >= ngroups) return;

    bf16x8 Bf[4][2];
#pragma unroll
    for (int nt = 0; nt < 4; ++nt)
#pragma unroll
        for (int kt = 0; kt < 2; ++kt) {
            bf16x8 f;
#pragma unroll
            for (int j = 0; j < 8; ++j)
                f[j] = (__bf16)Wp[(kt * 32 + q * 8 + j) * DIM + nt * 16 + t];
            Bf[nt][kt] = f;
        }
    float cv[4], bv[4];
#pragma unroll
    for (int nt = 0; nt < 4; ++nt) {
        cv[nt] = c[nt * 16 + t];
        bv[nt] = b2[nt * 16 + t];
    }

    auto loadA = [&](int r0, f32x4* raw) {
        int row = r0 + t;
        if (row >= n) row = n - 1;
        const __bf16* xr = z + (size_t)row * DIM;
        raw[0] = *(const f32x4*)(xr + q * 8);
        raw[1] = *(const f32x4*)(xr + 32 + q * 8);
    };

    f32x4 cur[2];
    loadA(g0 * 16, cur);

#pragma unroll 1
    for (int gi = 0; gi < GPW; ++gi) {
        int g = g0 + gi;
        if (g >= ngroups) break;
        int r0 = g * 16;
        f32x4 nxt[2];
        bool pf = (gi + 1 < GPW) && (g + 1 < ngroups);
        if (pf) loadA(r0 + 16, nxt);

        bf16x8 A0 = __builtin_bit_cast(bf16x8, cur[0]);
        bf16x8 A1 = __builtin_bit_cast(bf16x8, cur[1]);

        f32x4 zf = {0.f, 0.f, 0.f, 0.f};
        f32x4 acc[4];
#pragma unroll
        for (int nt = 0; nt < 4; ++nt)
            acc[nt] = mfma16(A1, Bf[nt][1], mfma16(A0, Bf[nt][0], zf));

        f32x4 r4 = *(const f32x4*)(r + r0 + q * 4);
#pragma unroll
        for (int nt = 0; nt < 4; ++nt)
#pragma unroll
            for (int reg = 0; reg < 4; ++reg) {
                int row = r0 + q * 4 + reg;
                if (row < n)
                    out[(size_t)row * DIM + nt * 16 + t] =
                        acc[nt][reg] + fmaf(r4[reg], cv[nt], bv[nt]);
            }
        cur[0] = nxt[0]; cur[1] = nxt[1];
    }
}

static inline size_t align16(size_t x) { return (x + 15) & ~(size_t)15; }

extern "C" void kernel_launch(void* const* d_in, const int* in_sizes, int n_in,
                              void* d_out, int out_size, void* d_ws, size_t ws_size,
                              hipStream_t stream) {
    const int* ei         = (const int*)d_in[0];
    const float* user_emb = (const float*)d_in[1];
    const float* item_emb = (const float*)d_in[2];
    const float* W1 = (const float*)d_in[3];
    const float* b1 = (const float*)d_in[4];
    const float* W2 = (const float*)d_in[5];
    const float* b2 = (const float*)d_in[6];
    float* out = (float*)d_out;

    const int E_ = in_sizes[0] / 2;
    const int NU = in_sizes[1] / DIM;
    const int NI = in_sizes[2] / DIM;
    const int N_ = NU + NI;
    const int NB = (N_ + BSPAN - 1) >> BSHIFT;
    const int NG = (N_ + 15) / 16;       // 16-row groups
    const int NP = NG * 16;              // padded row count

    // workspace layout (16B-aligned). Aliases:
    //   z aliases g      (g fully consumed by agg1 before agg2 writes z)
    //   packed aliases q (consumed by bucket_sort before agg1 writes q)
    char* p = (char*)d_ws;
    int* srcs   = (int*)p;               p += align16((size_t)E_ * 4);
    __bf16* g   = (__bf16*)p;            p += align16((size_t)NP * DIM * 2);
    __bf16* q   = (__bf16*)p;            p += align16((size_t)NP * DIM * 2);
    float* dinv = (float*)p;             p += align16((size_t)NP * 4);
    float* rvec = (float*)p;             p += align16((size_t)NP * 4);
    int* rowptr = (int*)p;               p += align16((size_t)(N_ + 1) * 4);
    int* bcnt   = (int*)p;               p += align16((size_t)MAXNB * 4);
    int* bptr   = (int*)p;               p += align16((size_t)(MAXNB + 1) * 4);
    int* bcur   = (int*)p;               p += align16((size_t)MAXNB * 4);
    float* Wp   = (float*)p;             p += align16((size_t)DIM * DIM * 4);
    float* cvec = (float*)p;             p += align16((size_t)DIM * 4);
    __bf16* zrow = g;                    // alias
    unsigned* packed = (unsigned*)q;     // alias

    zerob_kernel<<<1, MAXNB, 0, stream>>>(bcnt);
    bucket_count_kernel<<<256, 512, 0, stream>>>(ei, bcnt, E_, NB);
    bucket_scan_kernel<<<1, 512, 0, stream>>>(bcnt, bptr, bcur, rowptr, NB, N_, E_);
    scatter_kernel<<<256, 512, 0, stream>>>(ei, bcur, packed, E_, NB);
    bucket_sort_kernel<<<NB, 256, 0, stream>>>(packed, bptr, rowptr, srcs, dinv, N_);
    prep_kernel<<<1, 256, 0, stream>>>(W1, W2, b1, Wp, cvec);

    int cblocks = ((N_ * 8) + 255) / 256;
    int ablocks = (N_ + 3) / 4;
    int gblocks = (NG + 4 * GPW - 1) / (4 * GPW);

    cast_kernel<<<cblocks, 256, 0, stream>>>(user_emb, item_emb, NU, dinv, g, N_);
    agg_kernel<true><<<ablocks, 256, 0, stream>>>(rowptr, srcs, g, dinv, q, rvec, N_);
    agg_kernel<false><<<ablocks, 256, 0, stream>>>(rowptr, srcs, q, dinv, zrow, nullptr, N_);
    gemm_kernel<<<gblocks, 256, 0, stream>>>(zrow, Wp, cvec, b2, rvec, out, N_, NG);
}

// Round 4
// 255.004 us; speedup vs baseline: 1.3629x; 1.3629x over previous
//
#include <hip/hip_runtime.h>

#define DIM 64
#define GPW 4    // 16-row groups per wave in gemm
#define BSHIFT 9
#define BSPAN 512      // nodes per bucket
#define MAXNB 512      // max buckets (N <= 262144; here N=200000 -> NB=391)

typedef __attribute__((ext_vector_type(8))) __bf16 bf16x8;
typedef __attribute__((ext_vector_type(4))) __bf16 bf16x4;
typedef __attribute__((ext_vector_type(8))) unsigned short u16x8;
typedef __attribute__((ext_vector_type(4))) float f32x4;

__device__ __forceinline__ f32x4 mfma16(bf16x8 a, bf16x8 b, f32x4 c) {
    return __builtin_amdgcn_mfma_f32_16x16x32_bf16(a, b, c, 0, 0, 0);
}

__device__ __forceinline__ float bf2f(unsigned short u) {
    return __uint_as_float((unsigned)u << 16);
}

// ---------- hierarchical CSR build (bucket -> node counting sort) ----------

__global__ void zerob_kernel(int* __restrict__ b) { b[threadIdx.x] = 0; }

__global__ __launch_bounds__(512) void bucket_count_kernel(
    const int* __restrict__ ei, int* __restrict__ bcnt, int E_, int NB) {
    __shared__ int hist[MAXNB];
    int tid = threadIdx.x;
    for (int i = tid; i < NB; i += 512) hist[i] = 0;
    __syncthreads();
    int chunk = (E_ + gridDim.x - 1) / gridDim.x;
    int e0 = blockIdx.x * chunk, e1 = min(E_, e0 + chunk);
    for (int e = e0 + tid; e < e1; e += 512)
        atomicAdd(&hist[ei[E_ + e] >> BSHIFT], 1);
    __syncthreads();
    for (int i = tid; i < NB; i += 512)
        if (hist[i]) atomicAdd(&bcnt[i], hist[i]);
}

__global__ __launch_bounds__(512) void bucket_scan_kernel(
    const int* __restrict__ bcnt, int* __restrict__ bptr, int* __restrict__ bcur,
    int* __restrict__ rowptr, int NB, int N_, int E_) {
    __shared__ int sm[512];
    int tid = threadIdx.x;
    int v = (tid < NB) ? bcnt[tid] : 0;
    sm[tid] = v;
    __syncthreads();
    for (int off = 1; off < 512; off <<= 1) {
        int t = 0;
        if (tid >= off) t = sm[tid - off];
        __syncthreads();
        if (tid >= off) sm[tid] += t;
        __syncthreads();
    }
    if (tid < NB) {
        int ex = sm[tid] - v;
        bptr[tid] = ex;
        bcur[tid] = ex;
    }
    if (tid == 0) { bptr[NB] = E_; rowptr[N_] = E_; }
}

__global__ __launch_bounds__(512) void scatter_kernel(
    const int* __restrict__ ei, int* __restrict__ bcur,
    unsigned* __restrict__ packed, int E_, int NB) {
    __shared__ int h[MAXNB];
    int tid = threadIdx.x;
    int chunk = (E_ + gridDim.x - 1) / gridDim.x;
    int e0 = blockIdx.x * chunk, e1 = min(E_, e0 + chunk);
    for (int i = tid; i < NB; i += 512) h[i] = 0;
    __syncthreads();
    for (int e = e0 + tid; e < e1; e += 512)
        atomicAdd(&h[ei[E_ + e] >> BSHIFT], 1);
    __syncthreads();
    for (int i = tid; i < NB; i += 512) {
        int c = h[i];
        h[i] = c ? atomicAdd(&bcur[i], c) : 0;
    }
    __syncthreads();
    for (int e = e0 + tid; e < e1; e += 512) {
        int s = ei[e], d = ei[E_ + e];
        int b = d >> BSHIFT;
        int pos = atomicAdd(&h[b], 1);
        packed[pos] = ((unsigned)s << BSHIFT) | (unsigned)(d & (BSPAN - 1));
    }
}

__global__ __launch_bounds__(256) void bucket_sort_kernel(
    const unsigned* __restrict__ packed, const int* __restrict__ bptr,
    int* __restrict__ rowptr, int* __restrict__ srcs,
    float* __restrict__ dinv, int N_) {
    __shared__ int cnt[BSPAN];
    __shared__ int sc[256];
    int tid = threadIdx.x;
    int b = blockIdx.x;
    int beg = bptr[b], end = bptr[b + 1];
    int node0 = b << BSHIFT;
    int nn = min(BSPAN, N_ - node0);
    cnt[tid] = 0; cnt[tid + 256] = 0;
    __syncthreads();
    for (int i = beg + tid; i < end; i += 256)
        atomicAdd(&cnt[packed[i] & (BSPAN - 1)], 1);
    __syncthreads();
    int degA = cnt[tid], degB = cnt[tid + 256];
    int a0 = cnt[2 * tid], a1 = cnt[2 * tid + 1];
    if (tid < nn) dinv[node0 + tid] = rsqrtf((float)(1 + degA));
    if (tid + 256 < nn) dinv[node0 + tid + 256] = rsqrtf((float)(1 + degB));
    int tot = a0 + a1;
    sc[tid] = tot;
    __syncthreads();
    for (int off = 1; off < 256; off <<= 1) {
        int t = 0;
        if (tid >= off) t = sc[tid - off];
        __syncthreads();
        if (tid >= off) sc[tid] += t;
        __syncthreads();
    }
    int ex = sc[tid] - tot;
    cnt[2 * tid] = ex;
    cnt[2 * tid + 1] = ex + a0;
    __syncthreads();
    if (tid < nn) rowptr[node0 + tid] = beg + cnt[tid];
    if (tid + 256 < nn) rowptr[node0 + tid + 256] = beg + cnt[tid + 256];
    __syncthreads();
    for (int i = beg + tid; i < end; i += 256) {
        unsigned p = packed[i];
        int pos = atomicAdd(&cnt[p & (BSPAN - 1)], 1);
        srcs[beg + pos] = (int)(p >> BSHIFT);
    }
}

// ---------- layer kernels ----------

// h'(bf16) = (x @ W) * dinv[row].   MFMA 16x16x32 bf16.
template <bool BF16IN>
__global__ __launch_bounds__(256) void gemm_kernel(
    const void* __restrict__ xa_, const void* __restrict__ xb_, int split,
    const float* __restrict__ W, const float* __restrict__ dinv,
    __bf16* __restrict__ h, int n, int ngroups) {
    int lane = threadIdx.x & 63;
    int q = lane >> 4, t = lane & 15;
    int wv = __builtin_amdgcn_readfirstlane(threadIdx.x >> 6);
    int g0 = (blockIdx.x * 4 + wv) * GPW;
    if (g0 >= ngroups) return;

    bf16x8 Bf[4][2];
#pragma unroll
    for (int nt = 0; nt < 4; ++nt)
#pragma unroll
        for (int kt = 0; kt < 2; ++kt) {
            bf16x8 f;
#pragma unroll
            for (int j = 0; j < 8; ++j)
                f[j] = (__bf16)W[(kt * 32 + q * 8 + j) * DIM + nt * 16 + t];
            Bf[nt][kt] = f;
        }

    auto loadA = [&](int r0, f32x4* raw) {
        int row = r0 + t;
        if (row >= n) row = n - 1;
        if constexpr (BF16IN) {
            const __bf16* xr = (const __bf16*)xa_ + (size_t)row * DIM;
            raw[0] = *(const f32x4*)(xr + q * 8);
            raw[1] = *(const f32x4*)(xr + 32 + q * 8);
        } else {
            const float* xr = (row < split)
                ? ((const float*)xa_ + (size_t)row * DIM)
                : ((const float*)xb_ + (size_t)(row - split) * DIM);
            raw[0] = *(const f32x4*)(xr + q * 8);
            raw[1] = *(const f32x4*)(xr + q * 8 + 4);
            raw[2] = *(const f32x4*)(xr + 32 + q * 8);
            raw[3] = *(const f32x4*)(xr + 32 + q * 8 + 4);
        }
    };

    f32x4 cur[4];
    loadA(g0 * 16, cur);

#pragma unroll 1
    for (int gi = 0; gi < GPW; ++gi) {
        int g = g0 + gi;
        if (g >= ngroups) break;
        int r0 = g * 16;
        f32x4 nxt[4];
        bool pf = (gi + 1 < GPW) && (g + 1 < ngroups);
        if (pf) loadA(r0 + 16, nxt);

        bf16x8 A0, A1;
        if constexpr (BF16IN) {
            A0 = __builtin_bit_cast(bf16x8, cur[0]);
            A1 = __builtin_bit_cast(bf16x8, cur[1]);
        } else {
#pragma unroll
            for (int j = 0; j < 4; ++j) {
                A0[j] = (__bf16)cur[0][j]; A0[j + 4] = (__bf16)cur[1][j];
                A1[j] = (__bf16)cur[2][j]; A1[j + 4] = (__bf16)cur[3][j];
            }
        }

        f32x4 z = {0.f, 0.f, 0.f, 0.f};
        f32x4 acc[4];
#pragma unroll
        for (int nt = 0; nt < 4; ++nt)
            acc[nt] = mfma16(A1, Bf[nt][1], mfma16(A0, Bf[nt][0], z));

        f32x4 d4 = *(const f32x4*)(dinv + r0 + q * 4);
#pragma unroll
        for (int nt = 0; nt < 4; ++nt)
#pragma unroll
            for (int reg = 0; reg < 4; ++reg) {
                int row = r0 + q * 4 + reg;
                if (row < n)
                    h[(size_t)row * DIM + nt * 16 + t] =
                        (__bf16)(acc[nt][reg] * d4[reg]);
            }
#pragma unroll
        for (int i = 0; i < 4; ++i) cur[i] = nxt[i];
    }
}

// out[node] = b + dinv[node] * (h'[node] + sum_s h'[s])
// 8 nodes per wave: wave = 8 groups x 8 lanes; each group owns one node's
// FULL 64-dim row (8 lanes x ushort8 = 128 B/row-load). Group preloads up
// to 8 edge ids in one coalesced srcs read, broadcasts via shfl, issues 8
// independent 16 B gathers (1 KB in flight/group), accumulates across
// edges IN REGISTERS (no cross-lane reduce). 8x fewer dependent
// rowptr->srcs->gather chains than one-node-per-wave.
template <typename OutT>
__global__ __launch_bounds__(256) void agg_kernel(
    const int* __restrict__ rowptr, const int* __restrict__ srcs,
    const __bf16* __restrict__ h, const float* __restrict__ bias,
    const float* __restrict__ dinv, OutT* __restrict__ out, int n) {
    int lane = threadIdx.x & 63;
    int t8 = lane & 7;           // dim octet: dims t8*8 .. t8*8+7
    int wv = threadIdx.x >> 6;
    int node = (blockIdx.x * 4 + wv) * 8 + (lane >> 3);
    bool alive = node < n;
    int nd = alive ? node : (n - 1);
    int beg = rowptr[nd], end = rowptr[nd + 1];

    // self row
    u16x8 sv = *(const u16x8*)(h + (size_t)nd * DIM + t8 * 8);
    float acc[8];
#pragma unroll
    for (int j = 0; j < 8; ++j) acc[j] = bf2f(sv[j]);

    int i = beg;
    while (i < end) {            // group-uniform loop (beg/end uniform per group)
        int idx = i + t8;
        int sl = (idx < end) ? srcs[idx] : 0;   // 8 slots, one coalesced read
        u16x8 vv[8];
#pragma unroll
        for (int k = 0; k < 8; ++k) {
            int s = __shfl(sl, (lane & 56) | k);   // group-local broadcast
            // unconditional load: invalid slots read row 0 (safe, L1-hot)
            vv[k] = *(const u16x8*)(h + (size_t)s * DIM + t8 * 8);
        }
#pragma unroll
        for (int k = 0; k < 8; ++k)
            if (i + k < end) {
#pragma unroll
                for (int j = 0; j < 8; ++j) acc[j] += bf2f(vv[k][j]);
            }
        i += 8;
    }

    float dn = dinv[nd];
    f32x4 b0 = *(const f32x4*)(bias + t8 * 8);
    f32x4 b1 = *(const f32x4*)(bias + t8 * 8 + 4);
    float r[8];
#pragma unroll
    for (int j = 0; j < 4; ++j) {
        r[j]     = fmaf(dn, acc[j],     b0[j]);
        r[j + 4] = fmaf(dn, acc[j + 4], b1[j]);
    }
    if (alive) {
        if constexpr (sizeof(OutT) == 4) {
            f32x4 o0 = {r[0], r[1], r[2], r[3]};
            f32x4 o1 = {r[4], r[5], r[6], r[7]};
            float* op = (float*)out + (size_t)node * DIM + t8 * 8;
            *(f32x4*)op = o0;
            *(f32x4*)(op + 4) = o1;
        } else {
            bf16x8 o;
#pragma unroll
            for (int j = 0; j < 8; ++j) o[j] = (__bf16)r[j];
            *(bf16x8*)((__bf16*)out + (size_t)node * DIM + t8 * 8) = o;
        }
    }
}

static inline size_t align16(size_t x) { return (x + 15) & ~(size_t)15; }

extern "C" void kernel_launch(void* const* d_in, const int* in_sizes, int n_in,
                              void* d_out, int out_size, void* d_ws, size_t ws_size,
                              hipStream_t stream) {
    const int* ei         = (const int*)d_in[0];
    const float* user_emb = (const float*)d_in[1];
    const float* item_emb = (const float*)d_in[2];
    const float* W1 = (const float*)d_in[3];
    const float* b1 = (const float*)d_in[4];
    const float* W2 = (const float*)d_in[5];
    const float* b2 = (const float*)d_in[6];
    float* out = (float*)d_out;

    const int E_ = in_sizes[0] / 2;
    const int NU = in_sizes[1] / DIM;
    const int NI = in_sizes[2] / DIM;
    const int N_ = NU + NI;
    const int NB = (N_ + BSPAN - 1) >> BSHIFT;

    // workspace layout (16B-aligned)
    char* p = (char*)d_ws;
    int* srcs   = (int*)p;               p += align16((size_t)E_ * 4);
    __bf16* h   = (__bf16*)p;            p += align16((size_t)N_ * DIM * 2);
    __bf16* t1  = (__bf16*)p;            p += align16((size_t)N_ * DIM * 2);
    float* dinv = (float*)p;             p += align16((size_t)N_ * 4);
    int* rowptr = (int*)p;               p += align16((size_t)(N_ + 1) * 4);
    int* bcnt   = (int*)p;               p += align16((size_t)MAXNB * 4);
    int* bptr   = (int*)p;               p += align16((size_t)(MAXNB + 1) * 4);
    int* bcur   = (int*)p;               p += align16((size_t)MAXNB * 4);
    // packed edge buffer aliases t1: fully consumed by bucket_sort before
    // agg1 writes t1.
    unsigned* packed = (unsigned*)t1;

    zerob_kernel<<<1, MAXNB, 0, stream>>>(bcnt);
    bucket_count_kernel<<<256, 512, 0, stream>>>(ei, bcnt, E_, NB);
    bucket_scan_kernel<<<1, 512, 0, stream>>>(bcnt, bptr, bcur, rowptr, NB, N_, E_);
    scatter_kernel<<<256, 512, 0, stream>>>(ei, bcur, packed, E_, NB);
    bucket_sort_kernel<<<NB, 256, 0, stream>>>(packed, bptr, rowptr, srcs, dinv, N_);

    int NG = (N_ + 15) / 16;                       // 16-row groups
    int gblocks = (NG + 4 * GPW - 1) / (4 * GPW);  // 4 waves/block
    int ablocks = (N_ + 31) / 32;                  // 32 nodes/block (8/wave)

    // layer 1
    gemm_kernel<false><<<gblocks, 256, 0, stream>>>(user_emb, item_emb, NU,
                                                    W1, dinv, h, N_, NG);
    agg_kernel<__bf16><<<ablocks, 256, 0, stream>>>(rowptr, srcs, h, b1, dinv, t1, N_);
    // layer 2
    gemm_kernel<true><<<gblocks, 256, 0, stream>>>(t1, t1, N_,
                                                   W2, dinv, h, N_, NG);
    agg_kernel<float><<<ablocks, 256, 0, stream>>>(rowptr, srcs, h, b2, dinv, out, N_);
}